// Round 1
// baseline (343.051 us; speedup 1.0000x reference)
//
#include <hip/hip_runtime.h>
#include <hip/hip_bf16.h>
#include <cstdint>

// Problem constants (match reference)
#define B_ 256
#define N_ 131072
#define D_ 256
#define INV_TEMP 20.0f   // 1/0.05
#define EPS_SM 1e-6f
#define EPS_LOG 1e-6f

// GEMM tiling
#define BN 128           // columns (cluster rows) per workgroup
#define BK 64            // K chunk
#define LDA 72           // LDS row stride (elems): 64 + 8 pad -> 2-way bank aliasing (free)
#define LDB 72
#define NSLOT 32         // atomic row-sum slots to spread contention

typedef __bf16 bf16_t;
typedef bf16_t bf16x8 __attribute__((ext_vector_type(8)));
typedef float f32x4 __attribute__((ext_vector_type(4)));

__device__ inline ushort f2bf(float f) {
  uint32_t u = __builtin_bit_cast(uint32_t, f);
  u += 0x7FFFu + ((u >> 16) & 1u);   // round to nearest even
  return (ushort)(u >> 16);
}

// One workgroup: all 256 rows x 128 columns. Computes exp(logit) row-wise
// partial sums and atomically accumulates into rowsum[slot][256].
__global__ __launch_bounds__(256, 2)
void gemm_rowsum(const float* __restrict__ inp, const float* __restrict__ cf,
                 float* __restrict__ rowsum) {
  __shared__ ushort As[256 * LDA];
  __shared__ ushort Bs[BN * LDB];
  const int tid  = threadIdx.x;
  const int wave = tid >> 6;
  const int lane = tid & 63;
  const int m15  = lane & 15;
  const int q    = lane >> 4;
  const int n0   = blockIdx.x * BN;

  f32x4 acc[4][8];
#pragma unroll
  for (int i = 0; i < 4; ++i)
#pragma unroll
    for (int j = 0; j < 8; ++j) acc[i][j] = (f32x4){0.f, 0.f, 0.f, 0.f};

  for (int kt = 0; kt < D_; kt += BK) {
    // Stage A tile: 256 x 64 fp32 -> bf16 LDS (coalesced: 16 lanes per row-seg)
#pragma unroll
    for (int j = 0; j < 16; ++j) {
      int i = j * 256 + tid;
      int row = i >> 4, c4 = i & 15;
      const float4 v = *(const float4*)(inp + row * D_ + kt + c4 * 4);
      ushort4 w = {f2bf(v.x), f2bf(v.y), f2bf(v.z), f2bf(v.w)};
      *(ushort4*)(&As[row * LDA + c4 * 4]) = w;
    }
    // Stage B tile: 128 x 64 fp32 -> bf16 LDS
#pragma unroll
    for (int j = 0; j < 8; ++j) {
      int i = j * 256 + tid;
      int row = i >> 4, c4 = i & 15;
      const float4 v = *(const float4*)(cf + (size_t)(n0 + row) * D_ + kt + c4 * 4);
      ushort4 w = {f2bf(v.x), f2bf(v.y), f2bf(v.z), f2bf(v.w)};
      *(ushort4*)(&Bs[row * LDB + c4 * 4]) = w;
    }
    __syncthreads();
#pragma unroll
    for (int ks = 0; ks < 2; ++ks) {
      bf16x8 af[4], bfr[8];
#pragma unroll
      for (int mb = 0; mb < 4; ++mb)
        af[mb] = __builtin_bit_cast(
            bf16x8, *(const uint4*)(&As[(wave * 64 + mb * 16 + m15) * LDA + ks * 32 + q * 8]));
#pragma unroll
      for (int nb = 0; nb < 8; ++nb)
        bfr[nb] = __builtin_bit_cast(
            bf16x8, *(const uint4*)(&Bs[(nb * 16 + m15) * LDB + ks * 32 + q * 8]));
#pragma unroll
      for (int mb = 0; mb < 4; ++mb)
#pragma unroll
        for (int nb = 0; nb < 8; ++nb)
          acc[mb][nb] = __builtin_amdgcn_mfma_f32_16x16x32_bf16(af[mb], bfr[nb], acc[mb][nb], 0, 0, 0);
    }
    __syncthreads();
  }

  // Epilogue: exp + per-row partial sums.
  // C/D layout (m89-verified): col = lane&15, row = (lane>>4)*4 + reg
  float rp[4][4];
#pragma unroll
  for (int mb = 0; mb < 4; ++mb)
#pragma unroll
    for (int r = 0; r < 4; ++r) rp[mb][r] = 0.f;
#pragma unroll
  for (int mb = 0; mb < 4; ++mb)
#pragma unroll
    for (int nb = 0; nb < 8; ++nb)
#pragma unroll
      for (int r = 0; r < 4; ++r)
        rp[mb][r] += __expf(acc[mb][nb][r] * INV_TEMP);
  // Reduce over the 16 lanes of each quad (these hold the 16 columns of a frag)
#pragma unroll
  for (int off = 8; off >= 1; off >>= 1)
#pragma unroll
    for (int mb = 0; mb < 4; ++mb)
#pragma unroll
      for (int r = 0; r < 4; ++r)
        rp[mb][r] += __shfl_xor(rp[mb][r], off, 64);

  if (m15 == 0) {
    float* slot = rowsum + (blockIdx.x & (NSLOT - 1)) * B_;
#pragma unroll
    for (int mb = 0; mb < 4; ++mb)
#pragma unroll
      for (int r = 0; r < 4; ++r)
        atomicAdd(&slot[wave * 64 + mb * 16 + q * 4 + r], rp[mb][r]);
  }
}

// Tiny kernel: exact fp32 target-column logits + final loss.
__global__ __launch_bounds__(256)
void finalize_loss(const float* __restrict__ inp, const float* __restrict__ cf,
                   const int* __restrict__ idx, const int* __restrict__ lab,
                   const float* __restrict__ rowsum, float* __restrict__ out) {
  __shared__ float red[256];
  const int b = threadIdx.x;
  const int t = lab[idx[b]];
  const float4* a = (const float4*)(inp + b * D_);
  const float4* c = (const float4*)(cf + (size_t)t * D_);
  float dot = 0.f;
#pragma unroll 8
  for (int i = 0; i < 64; ++i) {
    float4 x = a[i], y = c[i];
    dot += x.x * y.x + x.y * y.y + x.z * y.z + x.w * y.w;
  }
  float S = 0.f;
#pragma unroll
  for (int s = 0; s < NSLOT; ++s) S += rowsum[s * B_ + b];
  float logp = __logf(__expf(dot * INV_TEMP) / (S + EPS_SM) + EPS_LOG);
  red[b] = logp;
  __syncthreads();
  for (int off = 128; off >= 1; off >>= 1) {
    if (b < off) red[b] += red[b + off];
    __syncthreads();
  }
  if (b == 0) out[0] = -red[0] * (1.0f / 256.0f);
}

extern "C" void kernel_launch(void* const* d_in, const int* in_sizes, int n_in,
                              void* d_out, int out_size, void* d_ws, size_t ws_size,
                              hipStream_t stream) {
  const float* inp = (const float*)d_in[0];  // inputs [256,256]
  const float* cf  = (const float*)d_in[1];  // cluster_features [131072,256]
  // d_in[2] = instance_features: unused by the reference
  const int* idx = (const int*)d_in[3];      // indexes [256]
  const int* lab = (const int*)d_in[4];      // labels [131072]
  float* out = (float*)d_out;
  float* rowsum = (float*)d_ws;              // NSLOT * 256 floats

  hipMemsetAsync(rowsum, 0, NSLOT * B_ * sizeof(float), stream);
  gemm_rowsum<<<dim3(N_ / BN), dim3(256), 0, stream>>>(inp, cf, rowsum);
  finalize_loss<<<dim3(1), dim3(256), 0, stream>>>(inp, cf, idx, lab, rowsum, out);
}

// Round 2
// 287.783 us; speedup vs baseline: 1.1920x; 1.1920x over previous
//
#include <hip/hip_runtime.h>
#include <hip/hip_bf16.h>
#include <cstdint>

// Problem constants (match reference)
#define B_ 256
#define N_ 131072
#define D_ 256
#define INV_TEMP 20.0f   // 1/0.05
#define EPS_SM 1e-6f
#define EPS_LOG 1e-6f

// GEMM tiling
#define TPB 512          // 8 waves; wave w owns rows w*32..w*32+31
#define BN 128           // cf rows per N-tile
#define BK 64            // K chunk
#define TILES 4          // N-tiles per block; grid = N_/(TILES*BN) = 256 blocks (1/CU)
#define LDB 72           // LDS row stride (elems): 64+8 pad -> 2-way bank aliasing (free), 16B-aligned rows
#define BUFE (BN * LDB)  // 9216 ushorts per buffer
#define NSLOT 32

typedef __bf16 bf16_t;
typedef bf16_t bf16x8 __attribute__((ext_vector_type(8)));
typedef float f32x4 __attribute__((ext_vector_type(4)));

__device__ inline ushort f2bf(float f) {
  uint32_t u = __builtin_bit_cast(uint32_t, f);
  u += 0x7FFFu + ((u >> 16) & 1u);   // round to nearest even
  return (ushort)(u >> 16);
}

__global__ __launch_bounds__(TPB, 2)
void gemm_rowsum(const float* __restrict__ inp, const float* __restrict__ cf,
                 float* __restrict__ rowsum) {
  // One 36 KB LDS region: phase 1 uses it as A-chunk [256][LDB]; steady state
  // as two B buffers of [128][LDB].
  __shared__ ushort smem[2 * BUFE];
  const int tid  = threadIdx.x;
  const int wave = tid >> 6;
  const int lane = tid & 63;
  const int m15  = lane & 15;
  const int q    = lane >> 4;

  // ---- Phase 1: A (inputs, 256x256 fp32) -> bf16 MFMA fragments in registers.
  // areg[kc*2+ks][mb] covers rows wave*32+mb*16+(lane&15), k = (kc*2+ks)*32 + q*8..+7
  bf16x8 areg[8][2];
#pragma unroll
  for (int kc = 0; kc < 4; ++kc) {
    const int row = tid >> 1, half = tid & 1;
    const float* src = inp + row * D_ + kc * BK + half * 32;
#pragma unroll
    for (int i = 0; i < 8; ++i) {
      const float4 v = *(const float4*)(src + i * 4);
      ushort4 w = {f2bf(v.x), f2bf(v.y), f2bf(v.z), f2bf(v.w)};
      *(ushort4*)(&smem[row * LDB + half * 32 + i * 4]) = w;
    }
    __syncthreads();
#pragma unroll
    for (int mb = 0; mb < 2; ++mb)
#pragma unroll
      for (int ks = 0; ks < 2; ++ks)
        areg[kc * 2 + ks][mb] = __builtin_bit_cast(
            bf16x8, *(const uint4*)(&smem[(wave * 32 + mb * 16 + m15) * LDB + ks * 32 + q * 8]));
    __syncthreads();
  }

  // ---- Steady state: stream cf in 16 chunks (tile=c>>2, kc=c&3), prefetch d=2.
  const size_t nbase = (size_t)blockIdx.x * (TILES * BN);
  const int brow = tid >> 2, bcg = tid & 3;  // 8192-elem chunk: 4 threads/row x 16 cols

  f32x4 acc[2][8];
  float rs[2][4];
#pragma unroll
  for (int mb = 0; mb < 2; ++mb) {
#pragma unroll
    for (int nb = 0; nb < 8; ++nb) acc[mb][nb] = (f32x4){0.f, 0.f, 0.f, 0.f};
#pragma unroll
    for (int r = 0; r < 4; ++r) rs[mb][r] = 0.f;
  }

  float4 ldbuf[2][4];  // two in-flight chunks (parity = chunk parity)
#define LDADDR(c) (cf + (nbase + (size_t)((c) >> 2) * BN + brow) * D_ + ((c) & 3) * BK + bcg * 16)

  // Prologue: chunk0 + chunk1 loads; chunk0 -> buf0
#pragma unroll
  for (int i = 0; i < 4; ++i) ldbuf[0][i] = *(const float4*)(LDADDR(0) + i * 4);
#pragma unroll
  for (int i = 0; i < 4; ++i) ldbuf[1][i] = *(const float4*)(LDADDR(1) + i * 4);
  {
    ushort* dst = &smem[0 * BUFE + brow * LDB + bcg * 16];
#pragma unroll
    for (int i = 0; i < 4; ++i) {
      const float4 v = ldbuf[0][i];
      ushort4 w = {f2bf(v.x), f2bf(v.y), f2bf(v.z), f2bf(v.w)};
      *(ushort4*)(dst + i * 4) = w;
    }
  }

#pragma unroll
  for (int c = 0; c < TILES * 4; ++c) {
    __syncthreads();  // buf[c&1] ready; prior reads of buf[(c+1)&1] drained
    if (c + 2 < TILES * 4) {
#pragma unroll
      for (int i = 0; i < 4; ++i) ldbuf[c & 1][i] = *(const float4*)(LDADDR(c + 2) + i * 4);
    }
    const ushort* bs = &smem[(c & 1) * BUFE];
#pragma unroll
    for (int ks = 0; ks < 2; ++ks) {
      bf16x8 bfr[8];
#pragma unroll
      for (int nb = 0; nb < 8; ++nb)
        bfr[nb] = __builtin_bit_cast(
            bf16x8, *(const uint4*)(&bs[(nb * 16 + m15) * LDB + ks * 32 + q * 8]));
#pragma unroll
      for (int mb = 0; mb < 2; ++mb)
#pragma unroll
        for (int nb = 0; nb < 8; ++nb)
          acc[mb][nb] = __builtin_amdgcn_mfma_f32_16x16x32_bf16(
              areg[(c & 3) * 2 + ks][mb], bfr[nb], acc[mb][nb], 0, 0, 0);
    }
    if ((c & 3) == 3) {  // tile finished: fold exp into register row-sums
#pragma unroll
      for (int mb = 0; mb < 2; ++mb)
#pragma unroll
        for (int nb = 0; nb < 8; ++nb)
#pragma unroll
          for (int r = 0; r < 4; ++r)
            rs[mb][r] += __expf(acc[mb][nb][r] * INV_TEMP);
      if (c + 1 < TILES * 4) {
#pragma unroll
        for (int mb = 0; mb < 2; ++mb)
#pragma unroll
          for (int nb = 0; nb < 8; ++nb) acc[mb][nb] = (f32x4){0.f, 0.f, 0.f, 0.f};
      }
    }
    if (c + 1 < TILES * 4) {  // convert+write chunk c+1 (loads landed long ago)
      ushort* dst = &smem[((c + 1) & 1) * BUFE + brow * LDB + bcg * 16];
#pragma unroll
      for (int i = 0; i < 4; ++i) {
        const float4 v = ldbuf[(c + 1) & 1][i];
        ushort4 w = {f2bf(v.x), f2bf(v.y), f2bf(v.z), f2bf(v.w)};
        *(ushort4*)(dst + i * 4) = w;
      }
    }
  }

  // C/D layout: col = lane&15, row = wave*32 + mb*16 + q*4 + r. Reduce cols
  // (nb already folded; now the 16 lanes of each quad) then one atomic batch.
#pragma unroll
  for (int off = 8; off >= 1; off >>= 1)
#pragma unroll
    for (int mb = 0; mb < 2; ++mb)
#pragma unroll
      for (int r = 0; r < 4; ++r)
        rs[mb][r] += __shfl_xor(rs[mb][r], off, 64);

  if (m15 == 0) {
    float* slot = rowsum + (blockIdx.x & (NSLOT - 1)) * B_;
#pragma unroll
    for (int mb = 0; mb < 2; ++mb)
#pragma unroll
      for (int r = 0; r < 4; ++r)
        atomicAdd(&slot[wave * 32 + mb * 16 + q * 4 + r], rs[mb][r]);
  }
#undef LDADDR
}

// Exact fp32 target-column logits + final loss. 1024 threads: 4 partials/row.
__global__ __launch_bounds__(1024)
void finalize_loss(const float* __restrict__ inp, const float* __restrict__ cf,
                   const int* __restrict__ idx, const int* __restrict__ lab,
                   const float* __restrict__ rowsum, float* __restrict__ out) {
  __shared__ float red[1024];
  __shared__ float lg[256];
  const int tid = threadIdx.x;
  const int b = tid >> 2, part = tid & 3;
  const int t = lab[idx[b]];
  const float4* a = (const float4*)(inp + b * D_ + part * 64);
  const float4* c = (const float4*)(cf + (size_t)t * D_ + part * 64);
  float dot = 0.f;
#pragma unroll
  for (int i = 0; i < 16; ++i) {
    const float4 x = a[i], y = c[i];
    dot += x.x * y.x + x.y * y.y + x.z * y.z + x.w * y.w;
  }
  red[tid] = dot;
  __syncthreads();
  if (tid < 256) {
    const float d = red[tid * 4] + red[tid * 4 + 1] + red[tid * 4 + 2] + red[tid * 4 + 3];
    float S = 0.f;
#pragma unroll
    for (int s = 0; s < NSLOT; ++s) S += rowsum[s * B_ + tid];
    lg[tid] = __logf(__expf(d * INV_TEMP) / (S + EPS_SM) + EPS_LOG);
  }
  __syncthreads();
  for (int off = 128; off >= 1; off >>= 1) {
    if (tid < off) lg[tid] += lg[tid + off];
    __syncthreads();
  }
  if (tid == 0) out[0] = -lg[0] * (1.0f / 256.0f);
}

extern "C" void kernel_launch(void* const* d_in, const int* in_sizes, int n_in,
                              void* d_out, int out_size, void* d_ws, size_t ws_size,
                              hipStream_t stream) {
  const float* inp = (const float*)d_in[0];  // inputs [256,256]
  const float* cf  = (const float*)d_in[1];  // cluster_features [131072,256]
  // d_in[2] = instance_features: unused by the reference
  const int* idx = (const int*)d_in[3];      // indexes [256]
  const int* lab = (const int*)d_in[4];      // labels [131072]
  float* out = (float*)d_out;
  float* rowsum = (float*)d_ws;              // NSLOT * 256 floats

  hipMemsetAsync(rowsum, 0, NSLOT * B_ * sizeof(float), stream);
  gemm_rowsum<<<dim3(N_ / (TILES * BN)), dim3(TPB), 0, stream>>>(inp, cf, rowsum);
  finalize_loss<<<dim3(1), dim3(1024), 0, stream>>>(inp, cf, idx, lab, rowsum, out);
}